// Round 3
// baseline (1261.057 us; speedup 1.0000x reference)
//
#include <hip/hip_runtime.h>
#include <hip/hip_bf16.h>

#define NB 4
#define CC 64
#define HW 4096
#define NT (NB*HW)
#define EPSV 1e-5f

// ws float layout: [0..255] raw stats (sumq,ssqq,sumk,ssqk), [256..511] folded
// scale/shift (sq,tq,sk,tk). Byte 2048+: fp32 yq[NB*CC*HW], yk, gv (12.6 MB).

__global__ void zero_stats_kernel(float* __restrict__ ws) { ws[threadIdx.x] = 0.0f; }

// ---------------------------------------------------------------------------
// Fused 1x1 convs + gate (+ optional stores) + BN stats accumulation.
// grid (HW/256, CC, NB), block 256. STORE=false: stats only (tiny-ws fallback).
// ---------------------------------------------------------------------------
template <bool STORE>
__global__ __launch_bounds__(256)
void conv3_kernel(const float* __restrict__ x,
                  const float* __restrict__ h0, const float* __restrict__ h1,
                  const float* __restrict__ Wq, const float* __restrict__ bq,
                  const float* __restrict__ Wk, const float* __restrict__ bk,
                  const float* __restrict__ Wv, const float* __restrict__ bv,
                  float* __restrict__ ws,
                  float* __restrict__ yq, float* __restrict__ yk, float* __restrict__ gv)
{
    __shared__ float Wql[CC], Wkl[CC], Wvl[CC];
    const int t = threadIdx.x;
    const int p = blockIdx.x * 256 + t;
    const int o = blockIdx.y;
    const int n = blockIdx.z;

    if (t < 64)                 Wql[t]     = Wq[o*CC + t];
    else if (t < 128)           Wkl[t-64]  = Wk[o*CC + (t-64)];
    else if (t < 192 && STORE)  Wvl[t-128] = Wv[o*CC + (t-128)];
    __syncthreads();

    float aq = bq[o];
    float ak = bk[o];
    float av = STORE ? bv[o] : 0.0f;

    const float* xp = x + (size_t)n*CC*HW + p;
    #pragma unroll
    for (int c = 0; c < CC; ++c) {
        float xv = xp[(size_t)c*HW];
        aq = fmaf(Wql[c], xv, aq);
        ak = fmaf(Wkl[c], xv, ak);
        if (STORE) av = fmaf(Wvl[c], xv, av);
    }

    if (STORE) {
        const size_t idx = (size_t)(n*CC + o)*HW + p;
        float g = h0[idx] + h1[idx];
        yq[idx] = aq;
        yk[idx] = ak;
        gv[idx] = g * av;
    }

    // BN stats from the fp32 conv outputs: wave reduce, lane-0 atomics
    float v0 = aq, v1 = aq*aq, v2 = ak, v3 = ak*ak;
    #pragma unroll
    for (int off = 32; off > 0; off >>= 1) {
        v0 += __shfl_down(v0, off);
        v1 += __shfl_down(v1, off);
        v2 += __shfl_down(v2, off);
        v3 += __shfl_down(v3, off);
    }
    if ((t & 63) == 0) {
        atomicAdd(&ws[      o], v0);
        atomicAdd(&ws[ 64 + o], v1);
        atomicAdd(&ws[128 + o], v2);
        atomicAdd(&ws[192 + o], v3);
    }
}

// ---------------------------------------------------------------------------
// Fold BN mean/var + gamma/beta into per-channel scale & shift.
// ---------------------------------------------------------------------------
__global__ void bnstats_kernel(const float* __restrict__ gq, const float* __restrict__ betaq,
                               const float* __restrict__ gk, const float* __restrict__ betak,
                               float* __restrict__ ws)
{
    const int i = threadIdx.x;
    if (i < 64) {
        float mean = ws[i] * (1.0f / NT);
        float var  = ws[64 + i] * (1.0f / NT) - mean*mean;
        float s    = gq[i] * rsqrtf(var + EPSV);
        ws[256 + i] = s;
        ws[320 + i] = betaq[i] - mean*s;
    } else if (i < 128) {
        int c = i - 64;
        float mean = ws[128 + c] * (1.0f / NT);
        float var  = ws[192 + c] * (1.0f / NT) - mean*mean;
        float s    = gk[c] * rsqrtf(var + EPSV);
        ws[384 + c] = s;
        ws[448 + c] = betak[c] - mean*s;
    }
}

// ---------------------------------------------------------------------------
// Flash attention, materialized path. 64 query rows/block, 256 threads.
// Thread t: ci=t&7 -> 8 channels, rl=t>>3 -> rows 2rl,2rl+1. TK=64 key tile.
// ---------------------------------------------------------------------------
#define TK   64
#define FKLD 68   // 64 + 4 pad, keeps float4 alignment; breaks >=4-way conflicts

__global__ __launch_bounds__(256)
void attn_mat_kernel(const float* __restrict__ ws,
                     const float* __restrict__ yq, const float* __restrict__ yk,
                     const float* __restrict__ gv, float* __restrict__ out)
{
    __shared__ __align__(16) float Ks [TK*FKLD];
    __shared__ __align__(16) float GVs[TK*FKLD];
    __shared__ float skl[CC], tkl[CC];

    const int t  = threadIdx.x;
    const int n  = blockIdx.y;
    const int ci = t & 7;
    const int rl = t >> 3;
    const int r0 = blockIdx.x * 64 + rl * 2;
    const int r1 = r0 + 1;

    if (t < 64)       skl[t]    = ws[384 + t];
    else if (t < 128) tkl[t-64] = ws[448 + (t-64)];

    const float* yqn = yq + (size_t)n*CC*HW;
    const float* ykn = yk + (size_t)n*CC*HW;
    const float* gvn = gv + (size_t)n*CC*HW;

    float q0[8], q1[8], O0[8], O1[8];
    #pragma unroll
    for (int j = 0; j < 8; ++j) {
        int c = ci*8 + j;
        float s  = ws[256 + c];
        float tt = ws[320 + c];
        q0[j] = fmaxf(fmaf(yqn[(size_t)c*HW + r0], s, tt), 0.0f);
        q1[j] = fmaxf(fmaf(yqn[(size_t)c*HW + r1], s, tt), 0.0f);
        O0[j] = 0.0f; O1[j] = 0.0f;
    }
    float m0 = -INFINITY, m1 = -INFINITY, l0 = 0.0f, l1 = 0.0f;

    for (int k0 = 0; k0 < HW; k0 += TK) {
        __syncthreads();   // also covers skl/tkl on the first iteration
        for (int i = t; i < TK*CC; i += 256) {
            int kk = i & (TK - 1);
            int c  = i >> 6;
            Ks [kk*FKLD + c] = fmaxf(fmaf(ykn[(size_t)c*HW + k0 + kk], skl[c], tkl[c]), 0.0f);
            GVs[kk*FKLD + c] = gvn[(size_t)c*HW + k0 + kk];
        }
        __syncthreads();

        for (int kk = 0; kk < TK; ++kk) {
            float kv[8], gvv[8];
            *(float4*)&kv[0]  = *(const float4*)&Ks [kk*FKLD + ci*8];
            *(float4*)&kv[4]  = *(const float4*)&Ks [kk*FKLD + ci*8 + 4];
            *(float4*)&gvv[0] = *(const float4*)&GVs[kk*FKLD + ci*8];
            *(float4*)&gvv[4] = *(const float4*)&GVs[kk*FKLD + ci*8 + 4];

            float s0p = 0.0f, s1p = 0.0f;
            #pragma unroll
            for (int j = 0; j < 8; ++j) {
                s0p = fmaf(q0[j], kv[j], s0p);
                s1p = fmaf(q1[j], kv[j], s1p);
            }
            #pragma unroll
            for (int off = 1; off < 8; off <<= 1) {
                s0p += __shfl_xor(s0p, off);
                s1p += __shfl_xor(s1p, off);
            }

            float mn0 = fmaxf(m0, s0p);
            float a0  = __expf(m0 - mn0);
            float p0  = __expf(s0p - mn0);
            l0 = fmaf(l0, a0, p0);  m0 = mn0;

            float mn1 = fmaxf(m1, s1p);
            float a1  = __expf(m1 - mn1);
            float p1  = __expf(s1p - mn1);
            l1 = fmaf(l1, a1, p1);  m1 = mn1;

            #pragma unroll
            for (int j = 0; j < 8; ++j) {
                O0[j] = fmaf(O0[j], a0, p0*gvv[j]);
                O1[j] = fmaf(O1[j], a1, p1*gvv[j]);
            }
        }
    }

    const float il0 = 1.0f / l0, il1 = 1.0f / l1;
    float* op = out + (size_t)n*CC*HW;
    #pragma unroll
    for (int j = 0; j < 8; ++j) {
        int c = ci*8 + j;
        op[(size_t)c*HW + r0] = O0[j] * il0;
        op[(size_t)c*HW + r1] = O1[j] * il1;
    }
}

// ---------------------------------------------------------------------------
// Fallback: scratch-free flash attention, recomputes the 1x1 convs on the fly.
// Only needs ws[0..511]. Used when ws_size can't hold the Y arrays.
// ---------------------------------------------------------------------------
#define FXLD 68   // fp32 leading dim for the x tile

__global__ __launch_bounds__(256)
void attn_fly_kernel(const float* __restrict__ x,
                     const float* __restrict__ h0, const float* __restrict__ h1,
                     const float* __restrict__ Wq, const float* __restrict__ bq,
                     const float* __restrict__ Wk, const float* __restrict__ bk,
                     const float* __restrict__ Wv, const float* __restrict__ bv,
                     const float* __restrict__ ws, float* __restrict__ out)
{
    __shared__ __align__(16) float Ks [TK*FKLD];
    __shared__ __align__(16) float GVs[TK*FKLD];
    __shared__ __align__(16) float xs [CC*FXLD];
    __shared__ float sql[CC], tql[CC], skl[CC], tkl[CC];

    const int t  = threadIdx.x;
    const int n  = blockIdx.y;
    const int qb = blockIdx.x;
    const int ci = t & 7;
    const int rl = t >> 3;
    const int r0 = qb*64 + rl*2;
    const int r1 = r0 + 1;

    if (t < 64) { sql[t] = ws[256+t]; tql[t] = ws[320+t]; skl[t] = ws[384+t]; tkl[t] = ws[448+t]; }

    const float* xn  = x  + (size_t)n*CC*HW;
    const float* h0n = h0 + (size_t)n*CC*HW;
    const float* h1n = h1 + (size_t)n*CC*HW;

    // stage x for the 64 query pixels, then build q in registers
    for (int i = t; i < CC*64; i += 256) {
        int c = i >> 6, p = i & 63;
        xs[c*FXLD + p] = xn[(size_t)c*HW + qb*64 + p];
    }
    __syncthreads();

    float q0[8], q1[8], O0[8], O1[8];
    #pragma unroll
    for (int j = 0; j < 8; ++j) {
        int c = ci*8 + j;
        float a0 = bq[c], a1 = a0;
        for (int ic = 0; ic < CC; ++ic) {
            float w = Wq[c*CC + ic];
            a0 = fmaf(w, xs[ic*FXLD + rl*2    ], a0);
            a1 = fmaf(w, xs[ic*FXLD + rl*2 + 1], a1);
        }
        q0[j] = fmaxf(fmaf(sql[c], a0, tql[c]), 0.0f);
        q1[j] = fmaxf(fmaf(sql[c], a1, tql[c]), 0.0f);
        O0[j] = 0.0f; O1[j] = 0.0f;
    }
    float m0 = -INFINITY, m1 = -INFINITY, l0 = 0.0f, l1 = 0.0f;

    for (int k0 = 0; k0 < HW; k0 += TK) {
        __syncthreads();    // everyone done with xs (q phase / previous tile)
        for (int i = t; i < CC*TK; i += 256) {
            int c = i >> 6, p = i & 63;
            xs[c*FXLD + p] = xn[(size_t)c*HW + k0 + p];
        }
        __syncthreads();
        // recompute K and gated-V for this tile (gate read straight from global)
        for (int i = t; i < CC*TK; i += 256) {
            int oc = i & 63, p = i >> 6;
            float ak = bk[oc], av = bv[oc];
            for (int ic = 0; ic < CC; ++ic) {
                float xv = xs[ic*FXLD + p];
                ak = fmaf(Wk[oc*CC + ic], xv, ak);
                av = fmaf(Wv[oc*CC + ic], xv, av);
            }
            size_t gi = (size_t)oc*HW + k0 + p;
            float g = h0n[gi] + h1n[gi];
            Ks [p*FKLD + oc] = fmaxf(fmaf(skl[oc], ak, tkl[oc]), 0.0f);
            GVs[p*FKLD + oc] = g * av;
        }
        __syncthreads();

        for (int kk = 0; kk < TK; ++kk) {
            float kv[8], gvv[8];
            *(float4*)&kv[0]  = *(const float4*)&Ks [kk*FKLD + ci*8];
            *(float4*)&kv[4]  = *(const float4*)&Ks [kk*FKLD + ci*8 + 4];
            *(float4*)&gvv[0] = *(const float4*)&GVs[kk*FKLD + ci*8];
            *(float4*)&gvv[4] = *(const float4*)&GVs[kk*FKLD + ci*8 + 4];

            float s0p = 0.0f, s1p = 0.0f;
            #pragma unroll
            for (int j = 0; j < 8; ++j) {
                s0p = fmaf(q0[j], kv[j], s0p);
                s1p = fmaf(q1[j], kv[j], s1p);
            }
            #pragma unroll
            for (int off = 1; off < 8; off <<= 1) {
                s0p += __shfl_xor(s0p, off);
                s1p += __shfl_xor(s1p, off);
            }

            float mn0 = fmaxf(m0, s0p);
            float a0  = __expf(m0 - mn0);
            float p0  = __expf(s0p - mn0);
            l0 = fmaf(l0, a0, p0);  m0 = mn0;

            float mn1 = fmaxf(m1, s1p);
            float a1  = __expf(m1 - mn1);
            float p1  = __expf(s1p - mn1);
            l1 = fmaf(l1, a1, p1);  m1 = mn1;

            #pragma unroll
            for (int j = 0; j < 8; ++j) {
                O0[j] = fmaf(O0[j], a0, p0*gvv[j]);
                O1[j] = fmaf(O1[j], a1, p1*gvv[j]);
            }
        }
    }

    const float il0 = 1.0f / l0, il1 = 1.0f / l1;
    float* op = out + (size_t)n*CC*HW;
    #pragma unroll
    for (int j = 0; j < 8; ++j) {
        int c = ci*8 + j;
        op[(size_t)c*HW + r0] = O0[j] * il0;
        op[(size_t)c*HW + r1] = O1[j] * il1;
    }
}

// ---------------------------------------------------------------------------
extern "C" void kernel_launch(void* const* d_in, const int* in_sizes, int n_in,
                              void* d_out, int out_size, void* d_ws, size_t ws_size,
                              hipStream_t stream)
{
    const float* low   = (const float*)d_in[0];
    const float* h0    = (const float*)d_in[1];
    const float* h1    = (const float*)d_in[2];
    const float* Wq    = (const float*)d_in[3];
    const float* bq    = (const float*)d_in[4];
    const float* gq    = (const float*)d_in[5];
    const float* betaq = (const float*)d_in[6];
    const float* Wk    = (const float*)d_in[7];
    const float* bk    = (const float*)d_in[8];
    const float* gk    = (const float*)d_in[9];
    const float* betak = (const float*)d_in[10];
    const float* Wv    = (const float*)d_in[11];
    const float* bv    = (const float*)d_in[12];

    float* wsf = (float*)d_ws;
    float* out = (float*)d_out;

    zero_stats_kernel<<<1, 256, 0, stream>>>(wsf);

    const size_t ybytes = (size_t)NB*CC*HW*sizeof(float);  // 4 MB each
    const size_t need   = 2048 + 3*ybytes;                 // 12.6 MB

    float* yq = (float*)((char*)d_ws + 2048);
    float* yk = yq + (size_t)NB*CC*HW;
    float* gv = yk + (size_t)NB*CC*HW;

    if (ws_size >= need) {
        conv3_kernel<true><<<dim3(HW/256, CC, NB), 256, 0, stream>>>(
            low, h0, h1, Wq, bq, Wk, bk, Wv, bv, wsf, yq, yk, gv);
        bnstats_kernel<<<1, 128, 0, stream>>>(gq, betaq, gk, betak, wsf);
        attn_mat_kernel<<<dim3(HW/64, NB), 256, 0, stream>>>(wsf, yq, yk, gv, out);
    } else {
        conv3_kernel<false><<<dim3(HW/256, CC, NB), 256, 0, stream>>>(
            low, h0, h1, Wq, bq, Wk, bk, Wv, bv, wsf, yq, yk, gv);
        bnstats_kernel<<<1, 128, 0, stream>>>(gq, betaq, gk, betak, wsf);
        attn_fly_kernel<<<dim3(HW/64, NB), 256, 0, stream>>>(
            low, h0, h1, Wq, bq, Wk, bk, Wv, bv, wsf, out);
    }
}

// Round 4
// 481.335 us; speedup vs baseline: 2.6199x; 2.6199x over previous
//
#include <hip/hip_runtime.h>
#include <hip/hip_bf16.h>

#define NB 4
#define CC 64
#define HW 4096
#define NT (NB*HW)
#define EPSV 1e-5f

typedef _Float16 f16;
typedef _Float16 half4 __attribute__((ext_vector_type(4)));
typedef float   float4v __attribute__((ext_vector_type(4)));

#define NELEM ((size_t)NB*HW*CC)   // 1,048,576 per tensor

// ws layout: fp32 ws[0..255] raw stats (sumq,ssqq,sumk,ssqk), ws[256..511]
// folded scale/shift (sq,tq,sk,tk). Byte 2048+: f16 qh, ql, kh, kl (layout
// [n][hw][c]) then gv (layout [n][c][hw]) — 5 x 2 MB = 10.49 MB total.

__global__ void zero_stats_kernel(float* __restrict__ ws) { ws[threadIdx.x] = 0.0f; }

// ---------------------------------------------------------------------------
// conv2: all 3 1x1 convs for a 64-pixel tile; writes f16x2 splits of raw
// q,k (transposed to [hw][c]) and gated-v ([c][hw]). grid (HW/64, NB), 256 thr.
// Thread: px = t&63 (lane), grp = t>>6 (wave-uniform) -> 16 output channels.
// ---------------------------------------------------------------------------
__global__ __launch_bounds__(256)
void conv2_kernel(const float* __restrict__ x,
                  const float* __restrict__ h0, const float* __restrict__ h1,
                  const float* __restrict__ Wq, const float* __restrict__ bq,
                  const float* __restrict__ Wk, const float* __restrict__ bk,
                  const float* __restrict__ Wv, const float* __restrict__ bv,
                  f16* __restrict__ qh, f16* __restrict__ ql,
                  f16* __restrict__ kh, f16* __restrict__ kl,
                  f16* __restrict__ gv)
{
    __shared__ float xs[CC*64];
    const int t   = threadIdx.x;
    const int n   = blockIdx.y;
    const int px0 = blockIdx.x * 64;
    const int px  = t & 63;
    const int grp = t >> 6;          // wave-uniform
    const int oc0 = grp * 16;

    for (int i = t; i < CC*64; i += 256) {
        int ic = i >> 6, p = i & 63;
        xs[ic*64 + p] = x[((size_t)n*CC + ic)*HW + px0 + p];
    }
    __syncthreads();

    float aq[16], ak[16], av[16];
    #pragma unroll
    for (int j = 0; j < 16; ++j) { aq[j] = bq[oc0+j]; ak[j] = bk[oc0+j]; av[j] = bv[oc0+j]; }

    for (int ic = 0; ic < CC; ++ic) {
        float xv = xs[ic*64 + px];
        #pragma unroll
        for (int j = 0; j < 16; ++j) {
            aq[j] = fmaf(Wq[(oc0+j)*CC + ic], xv, aq[j]);
            ak[j] = fmaf(Wk[(oc0+j)*CC + ic], xv, ak[j]);
            av[j] = fmaf(Wv[(oc0+j)*CC + ic], xv, av[j]);
        }
    }

    const size_t row  = (size_t)n*HW + px0 + px;
    const size_t base = row*CC + oc0;
    #pragma unroll
    for (int j = 0; j < 16; ++j) {
        f16 h = (f16)aq[j];  qh[base+j] = h;  ql[base+j] = (f16)(aq[j] - (float)h);
        f16 g = (f16)ak[j];  kh[base+j] = g;  kl[base+j] = (f16)(ak[j] - (float)g);
    }
    #pragma unroll
    for (int j = 0; j < 16; ++j) {
        size_t gi = ((size_t)n*CC + oc0 + j)*HW + px0 + px;
        float gate = h0[gi] + h1[gi];
        gv[gi] = (f16)(gate * av[j]);
    }
}

// ---------------------------------------------------------------------------
// BN stats from the f16x2 splits (exactly the values attention will use).
// grid 256 blocks x 256 thr; thread: oc = t&63, rgrp = t>>6.
// ---------------------------------------------------------------------------
__global__ __launch_bounds__(256)
void stats_kernel(const f16* __restrict__ qh, const f16* __restrict__ ql,
                  const f16* __restrict__ kh, const f16* __restrict__ kl,
                  float* __restrict__ ws)
{
    __shared__ float sbuf[4][4][CC];
    const int t = threadIdx.x;
    const int oc = t & 63, rg = t >> 6;
    const size_t row0 = (size_t)blockIdx.x * 64;

    float sq = 0.f, sqq = 0.f, sk = 0.f, skk = 0.f;
    for (int r = rg; r < 64; r += 4) {
        size_t i = (row0 + r)*CC + oc;
        float q = (float)qh[i] + (float)ql[i];
        float k = (float)kh[i] + (float)kl[i];
        sq += q; sqq += q*q; sk += k; skk += k*k;
    }
    sbuf[0][rg][oc] = sq; sbuf[1][rg][oc] = sqq;
    sbuf[2][rg][oc] = sk; sbuf[3][rg][oc] = skk;
    __syncthreads();
    const int st = t >> 6, c = t & 63;
    float tot = sbuf[st][0][c] + sbuf[st][1][c] + sbuf[st][2][c] + sbuf[st][3][c];
    atomicAdd(&ws[st*64 + c], tot);
}

// ---------------------------------------------------------------------------
// Fold BN mean/var + gamma/beta into per-channel scale & shift.
// ---------------------------------------------------------------------------
__global__ void bnstats_kernel(const float* __restrict__ gq, const float* __restrict__ betaq,
                               const float* __restrict__ gk, const float* __restrict__ betak,
                               float* __restrict__ ws)
{
    const int i = threadIdx.x;
    if (i < 64) {
        float mean = ws[i] * (1.0f / NT);
        float var  = ws[64 + i] * (1.0f / NT) - mean*mean;
        float s    = gq[i] * rsqrtf(var + EPSV);
        ws[256 + i] = s;
        ws[320 + i] = betaq[i] - mean*s;
    } else if (i < 128) {
        int c = i - 64;
        float mean = ws[128 + c] * (1.0f / NT);
        float var  = ws[192 + c] * (1.0f / NT) - mean*mean;
        float s    = gk[c] * rsqrtf(var + EPSV);
        ws[384 + c] = s;
        ws[448 + c] = betak[c] - mean*s;
    }
}

// ---------------------------------------------------------------------------
// apply: in-place y = relu(s*(h+l)+t), re-split to f16x2. blockIdx.y: 0=q, 1=k.
// ---------------------------------------------------------------------------
__global__ __launch_bounds__(256)
void apply_kernel(f16* __restrict__ qh, f16* __restrict__ ql,
                  f16* __restrict__ kh, f16* __restrict__ kl,
                  const float* __restrict__ ws)
{
    __shared__ float sc[CC], sh[CC];
    const int t = threadIdx.x;
    const int tens = blockIdx.y;
    if (t < 64)       sc[t]    = ws[256 + tens*128 + t];
    else if (t < 128) sh[t-64] = ws[320 + tens*128 + (t-64)];
    __syncthreads();

    f16* ph = tens ? kh : qh;
    f16* pl = tens ? kl : ql;
    const size_t e0 = ((size_t)blockIdx.x * 256 + t) * 8;
    const int c0 = (int)(e0 & 63);

    half4 h0v = *(half4*)&ph[e0], h1v = *(half4*)&ph[e0+4];
    half4 l0v = *(half4*)&pl[e0], l1v = *(half4*)&pl[e0+4];
    half4 oh0, oh1, ol0, ol1;
    #pragma unroll
    for (int j = 0; j < 4; ++j) {
        float y = (float)h0v[j] + (float)l0v[j];
        float z = fmaxf(fmaf(sc[c0+j], y, sh[c0+j]), 0.0f);
        f16 zh = (f16)z; oh0[j] = zh; ol0[j] = (f16)(z - (float)zh);
        float y2 = (float)h1v[j] + (float)l1v[j];
        float z2 = fmaxf(fmaf(sc[c0+4+j], y2, sh[c0+4+j]), 0.0f);
        f16 zh2 = (f16)z2; oh1[j] = zh2; ol1[j] = (f16)(z2 - (float)zh2);
    }
    *(half4*)&ph[e0]   = oh0;  *(half4*)&ph[e0+4] = oh1;
    *(half4*)&pl[e0]   = ol0;  *(half4*)&pl[e0+4] = ol1;
}

// ---------------------------------------------------------------------------
// MFMA flash attention. grid (HW/32, NB), 256 thr (4 waves).
// wave w: rowtile = w&1 (16 query rows), khalf = w>>1 (2048 keys). Merge in LDS.
// ---------------------------------------------------------------------------
#define PLD 18   // f16 leading dim of P buffer (36 B rows -> conflict-light)

__global__ __launch_bounds__(256)
void attn_kernel(const f16* __restrict__ qh, const f16* __restrict__ ql,
                 const f16* __restrict__ kh, const f16* __restrict__ kl,
                 const f16* __restrict__ gv, const float* __restrict__ ws,
                 float* __restrict__ out)
{
    __shared__ f16   Pbuf[4][16][PLD];
    __shared__ float Obuf[2][16][68];
    __shared__ float mlbuf[2][2][16];

    const int t    = threadIdx.x;
    const int n    = blockIdx.y;
    const int w    = t >> 6;
    const int lane = t & 63;
    const int rt   = w & 1;          // row tile
    const int khalf= w >> 1;         // key half
    const int m16  = lane & 15;
    const int kb   = lane >> 4;      // quad

    const int qrow = blockIdx.x*32 + rt*16 + m16;
    const size_t qbase = ((size_t)n*HW + qrow)*CC;

    half4 aqh[4], aql[4];
    #pragma unroll
    for (int s = 0; s < 4; ++s) {
        aqh[s] = *(const half4*)&qh[qbase + s*16 + kb*4];
        aql[s] = *(const half4*)&ql[qbase + s*16 + kb*4];
    }

    const half4 ones = {(f16)1.f, (f16)1.f, (f16)1.f, (f16)1.f};
    float4v accO[4];
    #pragma unroll
    for (int ct = 0; ct < 4; ++ct) accO[ct] = (float4v){0.f,0.f,0.f,0.f};
    float m[4] = {-INFINITY,-INFINITY,-INFINITY,-INFINITY};
    float l[4] = {0.f,0.f,0.f,0.f};

    f16* Pw = &Pbuf[w][0][0];

    for (int it = 0; it < 128; ++it) {
        const int kt = khalf*2048 + it*16;
        const size_t kbase = ((size_t)n*HW + kt + m16)*CC;

        half4 bkh[4], bkl[4];
        #pragma unroll
        for (int s = 0; s < 4; ++s) {
            bkh[s] = *(const half4*)&kh[kbase + s*16 + kb*4];
            bkl[s] = *(const half4*)&kl[kbase + s*16 + kb*4];
        }

        float4v accS = (float4v){0.f,0.f,0.f,0.f};
        #pragma unroll
        for (int s = 0; s < 4; ++s)
            accS = __builtin_amdgcn_mfma_f32_16x16x16f16(aqh[s], bkh[s], accS, 0, 0, 0);
        #pragma unroll
        for (int s = 0; s < 4; ++s)
            accS = __builtin_amdgcn_mfma_f32_16x16x16f16(aql[s], bkh[s], accS, 0, 0, 0);
        #pragma unroll
        for (int s = 0; s < 4; ++s)
            accS = __builtin_amdgcn_mfma_f32_16x16x16f16(aqh[s], bkl[s], accS, 0, 0, 0);

        // online softmax per row r (row = kb*4 + r, col = m16)
        float alpha[4], p[4];
        #pragma unroll
        for (int r = 0; r < 4; ++r) {
            float sv = accS[r];
            sv = fmaxf(sv, __shfl_xor(sv, 1));
            sv = fmaxf(sv, __shfl_xor(sv, 2));
            sv = fmaxf(sv, __shfl_xor(sv, 4));
            sv = fmaxf(sv, __shfl_xor(sv, 8));
            float mn = fmaxf(m[r], sv);
            alpha[r] = __expf(m[r] - mn);
            p[r]     = __expf(accS[r] - mn);
            m[r]     = mn;
        }

        // P (C-layout) -> LDS [row][key]
        #pragma unroll
        for (int r = 0; r < 4; ++r)
            Pw[(kb*4 + r)*PLD + m16] = (f16)p[r];

        // rescale O, l by alpha
        #pragma unroll
        for (int r = 0; r < 4; ++r) l[r] *= alpha[r];
        #pragma unroll
        for (int ct = 0; ct < 4; ++ct)
            #pragma unroll
            for (int r = 0; r < 4; ++r) accO[ct][r] *= alpha[r];

        // same-wave DS ordering guard (drain lgkm before re-reading Pbuf)
        __builtin_amdgcn_s_waitcnt(0xC07F);

        // P as A-fragment: lane m16 -> row, kb*4+j -> key
        half4 pf = *(const half4*)&Pw[m16*PLD + kb*4];

        // row-sum via MFMA with ones
        float4v accL = __builtin_amdgcn_mfma_f32_16x16x16f16(
            pf, ones, (float4v){0.f,0.f,0.f,0.f}, 0, 0, 0);
        #pragma unroll
        for (int r = 0; r < 4; ++r) l[r] += accL[r];

        // PV: 4 channel tiles of 16
        #pragma unroll
        for (int ct = 0; ct < 4; ++ct) {
            half4 gvf = *(const half4*)&gv[((size_t)n*CC + ct*16 + m16)*HW + kt + kb*4];
            accO[ct] = __builtin_amdgcn_mfma_f32_16x16x16f16(pf, gvf, accO[ct], 0, 0, 0);
        }
    }

    // merge the two K-halves per row tile
    if (khalf == 1) {
        #pragma unroll
        for (int ct = 0; ct < 4; ++ct)
            #pragma unroll
            for (int r = 0; r < 4; ++r)
                Obuf[rt][kb*4 + r][ct*16 + m16] = accO[ct][r];
        if (m16 == 0) {
            #pragma unroll
            for (int r = 0; r < 4; ++r) {
                mlbuf[rt][0][kb*4 + r] = m[r];
                mlbuf[rt][1][kb*4 + r] = l[r];
            }
        }
    }
    __syncthreads();
    if (khalf == 0) {
        float f1[4], f2[4], inv[4];
        #pragma unroll
        for (int r = 0; r < 4; ++r) {
            float m2 = mlbuf[rt][0][kb*4 + r];
            float l2 = mlbuf[rt][1][kb*4 + r];
            float M  = fmaxf(m[r], m2);
            float e1 = __expf(m[r] - M);
            float e2 = __expf(m2  - M);
            float lt = l[r]*e1 + l2*e2;
            f1[r] = e1; f2[r] = e2; inv[r] = 1.0f / lt;
        }
        #pragma unroll
        for (int ct = 0; ct < 4; ++ct) {
            float4 o4;
            o4.x = (accO[ct][0]*f1[0] + Obuf[rt][kb*4+0][ct*16+m16]*f2[0]) * inv[0];
            o4.y = (accO[ct][1]*f1[1] + Obuf[rt][kb*4+1][ct*16+m16]*f2[1]) * inv[1];
            o4.z = (accO[ct][2]*f1[2] + Obuf[rt][kb*4+2][ct*16+m16]*f2[2]) * inv[2];
            o4.w = (accO[ct][3]*f1[3] + Obuf[rt][kb*4+3][ct*16+m16]*f2[3]) * inv[3];
            *(float4*)&out[((size_t)n*CC + ct*16 + m16)*HW + blockIdx.x*32 + rt*16 + kb*4] = o4;
        }
    }
}

// ---------------------------------------------------------------------------
extern "C" void kernel_launch(void* const* d_in, const int* in_sizes, int n_in,
                              void* d_out, int out_size, void* d_ws, size_t ws_size,
                              hipStream_t stream)
{
    const float* low   = (const float*)d_in[0];
    const float* h0    = (const float*)d_in[1];
    const float* h1    = (const float*)d_in[2];
    const float* Wq    = (const float*)d_in[3];
    const float* bq    = (const float*)d_in[4];
    const float* gq    = (const float*)d_in[5];
    const float* betaq = (const float*)d_in[6];
    const float* Wk    = (const float*)d_in[7];
    const float* bk    = (const float*)d_in[8];
    const float* gk    = (const float*)d_in[9];
    const float* betak = (const float*)d_in[10];
    const float* Wv    = (const float*)d_in[11];
    const float* bv    = (const float*)d_in[12];

    float* wsf = (float*)d_ws;
    float* out = (float*)d_out;

    f16* base = (f16*)((char*)d_ws + 2048);
    f16* qh = base;
    f16* ql = qh + NELEM;
    f16* kh = ql + NELEM;
    f16* kl = kh + NELEM;
    f16* gv = kl + NELEM;

    zero_stats_kernel<<<1, 256, 0, stream>>>(wsf);

    conv2_kernel<<<dim3(HW/64, NB), 256, 0, stream>>>(
        low, h0, h1, Wq, bq, Wk, bk, Wv, bv, qh, ql, kh, kl, gv);

    stats_kernel<<<NT/64, 256, 0, stream>>>(qh, ql, kh, kl, wsf);

    bnstats_kernel<<<1, 128, 0, stream>>>(gq, betaq, gk, betak, wsf);

    apply_kernel<<<dim3(NELEM/(256*8), 2), 256, 0, stream>>>(qh, ql, kh, kl, wsf);

    attn_kernel<<<dim3(HW/32, NB), 256, 0, stream>>>(qh, ql, kh, kl, gv, wsf, out);
}

// Round 5
// 461.168 us; speedup vs baseline: 2.7345x; 1.0437x over previous
//
#include <hip/hip_runtime.h>

#define NB 4
#define CC 64
#define HW 4096
#define NT (NB*HW)
#define EPSV 1e-5f

typedef _Float16 f16;
typedef _Float16 half4 __attribute__((ext_vector_type(4)));
typedef _Float16 half8 __attribute__((ext_vector_type(8)));
typedef float   float4v __attribute__((ext_vector_type(4)));

#define NELEM ((size_t)NB*HW*CC)   // 1,048,576 per tensor

// ws layout: fp32 ws[0..255] raw stats (sumq,ssqq,sumk,ssqk), ws[256..511]
// folded scale/shift (sq,tq,sk,tk). Byte 2048+: f16 qh, ql, kh, kl ([n][hw][c])
// then gv ([n][c][hw]) — 5 x 2 MB = 10.49 MB (ws_size >= this, proven r4).

__global__ void zero_stats_kernel(float* __restrict__ ws) { ws[threadIdx.x] = 0.0f; }

// ---------------------------------------------------------------------------
// conv2: 3 fused 1x1 convs for 64 pixels + f16x2 split stores + fused BN stats.
// grid (HW/64, NB), 512 thr. Wave grp = t>>6 owns 8 output channels; px = t&63.
// ---------------------------------------------------------------------------
__global__ __launch_bounds__(512)
void conv2_kernel(const float* __restrict__ x,
                  const float* __restrict__ h0, const float* __restrict__ h1,
                  const float* __restrict__ Wq, const float* __restrict__ bq,
                  const float* __restrict__ Wk, const float* __restrict__ bk,
                  const float* __restrict__ Wv, const float* __restrict__ bv,
                  float* __restrict__ ws,
                  f16* __restrict__ qh, f16* __restrict__ ql,
                  f16* __restrict__ kh, f16* __restrict__ kl,
                  f16* __restrict__ gv)
{
    __shared__ float xs[CC][64];
    const int t   = threadIdx.x;
    const int n   = blockIdx.y;
    const int px0 = blockIdx.x * 64;
    const int px  = t & 63;
    const int grp = t >> 6;          // wave index, wave-uniform
    const int oc0 = grp * 8;

    for (int i = t; i < CC*64; i += 512) {
        int ic = i >> 6, p = i & 63;
        xs[ic][p] = x[((size_t)n*CC + ic)*HW + px0 + p];
    }
    __syncthreads();

    float aq[8], ak[8], av[8];
    #pragma unroll
    for (int j = 0; j < 8; ++j) { aq[j] = bq[oc0+j]; ak[j] = bk[oc0+j]; av[j] = bv[oc0+j]; }

    for (int ic = 0; ic < CC; ++ic) {
        float xv = xs[ic][px];
        #pragma unroll
        for (int j = 0; j < 8; ++j) {
            aq[j] = fmaf(Wq[(oc0+j)*CC + ic], xv, aq[j]);
            ak[j] = fmaf(Wk[(oc0+j)*CC + ic], xv, ak[j]);
            av[j] = fmaf(Wv[(oc0+j)*CC + ic], xv, av[j]);
        }
    }

    // f16x2 split stores, [row][c] layout, half8-vectorized
    const size_t base = ((size_t)n*HW + px0 + px)*CC + oc0;
    half8 vqh, vql, vkh, vkl;
    #pragma unroll
    for (int j = 0; j < 8; ++j) {
        f16 hq = (f16)aq[j]; vqh[j] = hq; vql[j] = (f16)(aq[j] - (float)hq);
        f16 hk = (f16)ak[j]; vkh[j] = hk; vkl[j] = (f16)(ak[j] - (float)hk);
    }
    *(half8*)&qh[base] = vqh;  *(half8*)&ql[base] = vql;
    *(half8*)&kh[base] = vkh;  *(half8*)&kl[base] = vkl;

    #pragma unroll
    for (int j = 0; j < 8; ++j) {
        size_t gi = ((size_t)n*CC + oc0 + j)*HW + px0 + px;
        gv[gi] = (f16)((h0[gi] + h1[gi]) * av[j]);
    }

    // fused BN stats: full-wave (64-lane) reduce per channel, lane-0 atomics
    #pragma unroll
    for (int j = 0; j < 8; ++j) {
        float v0 = aq[j], v1 = aq[j]*aq[j], v2 = ak[j], v3 = ak[j]*ak[j];
        #pragma unroll
        for (int off = 32; off > 0; off >>= 1) {
            v0 += __shfl_down(v0, off);
            v1 += __shfl_down(v1, off);
            v2 += __shfl_down(v2, off);
            v3 += __shfl_down(v3, off);
        }
        if (px == 0) {
            atomicAdd(&ws[      oc0 + j], v0);
            atomicAdd(&ws[ 64 + oc0 + j], v1);
            atomicAdd(&ws[128 + oc0 + j], v2);
            atomicAdd(&ws[192 + oc0 + j], v3);
        }
    }
}

// ---------------------------------------------------------------------------
// Fold BN mean/var + gamma/beta into per-channel scale & shift.
// ---------------------------------------------------------------------------
__global__ void bnstats_kernel(const float* __restrict__ gq, const float* __restrict__ betaq,
                               const float* __restrict__ gk, const float* __restrict__ betak,
                               float* __restrict__ ws)
{
    const int i = threadIdx.x;
    if (i < 64) {
        float mean = ws[i] * (1.0f / NT);
        float var  = ws[64 + i] * (1.0f / NT) - mean*mean;
        float s    = gq[i] * rsqrtf(var + EPSV);
        ws[256 + i] = s;
        ws[320 + i] = betaq[i] - mean*s;
    } else if (i < 128) {
        int c = i - 64;
        float mean = ws[128 + c] * (1.0f / NT);
        float var  = ws[192 + c] * (1.0f / NT) - mean*mean;
        float s    = gk[c] * rsqrtf(var + EPSV);
        ws[384 + c] = s;
        ws[448 + c] = betak[c] - mean*s;
    }
}

// ---------------------------------------------------------------------------
// apply: in-place y = relu(s*(h+l)+t), re-split to f16x2. blockIdx.y: 0=q, 1=k.
// ---------------------------------------------------------------------------
__global__ __launch_bounds__(256)
void apply_kernel(f16* __restrict__ qh, f16* __restrict__ ql,
                  f16* __restrict__ kh, f16* __restrict__ kl,
                  const float* __restrict__ ws)
{
    __shared__ float sc[CC], sh[CC];
    const int t = threadIdx.x;
    const int tens = blockIdx.y;
    if (t < 64)       sc[t]    = ws[256 + tens*128 + t];
    else if (t < 128) sh[t-64] = ws[320 + tens*128 + (t-64)];
    __syncthreads();

    f16* ph = tens ? kh : qh;
    f16* pl = tens ? kl : ql;
    const size_t e0 = ((size_t)blockIdx.x * 256 + t) * 8;
    const int c0 = (int)(e0 & 63);

    half4 h0v = *(half4*)&ph[e0], h1v = *(half4*)&ph[e0+4];
    half4 l0v = *(half4*)&pl[e0], l1v = *(half4*)&pl[e0+4];
    half4 oh0, oh1, ol0, ol1;
    #pragma unroll
    for (int j = 0; j < 4; ++j) {
        float y = (float)h0v[j] + (float)l0v[j];
        float z = fmaxf(fmaf(sc[c0+j], y, sh[c0+j]), 0.0f);
        f16 zh = (f16)z; oh0[j] = zh; ol0[j] = (f16)(z - (float)zh);
        float y2 = (float)h1v[j] + (float)l1v[j];
        float z2 = fmaxf(fmaf(sc[c0+4+j], y2, sh[c0+4+j]), 0.0f);
        f16 zh2 = (f16)z2; oh1[j] = zh2; ol1[j] = (f16)(z2 - (float)zh2);
    }
    *(half4*)&ph[e0]   = oh0;  *(half4*)&ph[e0+4] = oh1;
    *(half4*)&pl[e0]   = ol0;  *(half4*)&pl[e0+4] = ol1;
}

// ---------------------------------------------------------------------------
// MFMA flash attention, S^T form, register-only K-loop with prefetch.
// grid (HW/16, NB), 256 thr. Wave w owns K-quarter [w*1024, +1024), all 4
// waves share the block's 16 Q rows; 4-way merge via LDS at the end.
// Layout convention (validated r4): mfma(X,Y) = X·Y^T with
//   D[p = quad*4+reg <- X's lane&15][q = lane&15 <- Y's lane&15].
// ---------------------------------------------------------------------------
__global__ __launch_bounds__(256)
void attn_kernel(const f16* __restrict__ qh, const f16* __restrict__ ql,
                 const f16* __restrict__ kh, const f16* __restrict__ kl,
                 const f16* __restrict__ gv, float* __restrict__ out)
{
    __shared__ float Obuf[3][64][16];          // waves 1..3 partial O^T
    __shared__ float Mbuf[3][16], Lbuf[3][16];

    const int t    = threadIdx.x;
    const int n    = blockIdx.y;
    const int w    = t >> 6;         // K-quarter
    const int lane = t & 63;
    const int m16  = lane & 15;      // q-row within tile / channel within ct
    const int kb   = lane >> 4;      // quad
    const int q0   = blockIdx.x * 16;

    // Q fragments (Y-operand): Y[q=qrow=lane&15][k=ch=kstep*32+kb*8+j]
    const size_t qb = ((size_t)n*HW + q0 + m16)*CC + kb*8;
    const half8 qhf0 = *(const half8*)&qh[qb];
    const half8 qhf1 = *(const half8*)&qh[qb + 32];
    const half8 qlf0 = *(const half8*)&ql[qb];
    const half8 qlf1 = *(const half8*)&ql[qb + 32];

    const int    kt0   = w * (HW/4);
    const size_t krow  = (size_t)n*HW*CC;
    const size_t gbase = ((size_t)n*CC + m16)*HW;

    half8 khf[2][2], klf[2][2];
    half4 gvf[2][4];

#define LOADK(B, KT) do {                                                   \
    size_t a_ = krow + ((size_t)(KT) + m16)*CC + kb*8;                      \
    khf[B][0] = *(const half8*)&kh[a_];                                     \
    khf[B][1] = *(const half8*)&kh[a_ + 32];                                \
    klf[B][0] = *(const half8*)&kl[a_];                                     \
    klf[B][1] = *(const half8*)&kl[a_ + 32];                                \
    size_t g_ = gbase + (size_t)(KT) + kb*4;                                \
    gvf[B][0] = *(const half4*)&gv[g_];                                     \
    gvf[B][1] = *(const half4*)&gv[g_ + (size_t)16*HW];                     \
    gvf[B][2] = *(const half4*)&gv[g_ + (size_t)32*HW];                     \
    gvf[B][3] = *(const half4*)&gv[g_ + (size_t)48*HW];                     \
} while (0)

    LOADK(0, kt0);

    float4v accO[4];
    #pragma unroll
    for (int ct = 0; ct < 4; ++ct) accO[ct] = (float4v){0.f,0.f,0.f,0.f};
    float m = -INFINITY, l = 0.0f;

    // One 16-key step on buffer B; optionally prefetch KTN into buffer NB_.
#define STEP(B, NB_, KTN, DO_PRE) do {                                      \
    if (DO_PRE) LOADK(NB_, KTN);                                            \
    float4v s1 = __builtin_amdgcn_mfma_f32_16x16x32_f16(                    \
        khf[B][0], qhf0, (float4v){0.f,0.f,0.f,0.f}, 0, 0, 0);              \
    s1 = __builtin_amdgcn_mfma_f32_16x16x32_f16(khf[B][1], qhf1, s1, 0,0,0);\
    float4v s2 = __builtin_amdgcn_mfma_f32_16x16x32_f16(                    \
        khf[B][0], qlf0, (float4v){0.f,0.f,0.f,0.f}, 0, 0, 0);              \
    s2 = __builtin_amdgcn_mfma_f32_16x16x32_f16(khf[B][1], qlf1, s2, 0,0,0);\
    float4v s3 = __builtin_amdgcn_mfma_f32_16x16x32_f16(                    \
        klf[B][0], qhf0, (float4v){0.f,0.f,0.f,0.f}, 0, 0, 0);              \
    s3 = __builtin_amdgcn_mfma_f32_16x16x32_f16(klf[B][1], qhf1, s3, 0,0,0);\
    float sc0 = s1[0]+s2[0]+s3[0], sc1 = s1[1]+s2[1]+s3[1];                 \
    float sc2 = s1[2]+s2[2]+s3[2], sc3 = s1[3]+s2[3]+s3[3];                 \
    float mx = fmaxf(fmaxf(sc0, sc1), fmaxf(sc2, sc3));                     \
    mx = fmaxf(mx, __shfl_xor(mx, 16));                                     \
    mx = fmaxf(mx, __shfl_xor(mx, 32));                                     \
    float mn = fmaxf(m, mx);                                                \
    float alpha = __expf(m - mn);  m = mn;                                  \
    float p0 = __expf(sc0 - mn), p1 = __expf(sc1 - mn);                     \
    float p2 = __expf(sc2 - mn), p3 = __expf(sc3 - mn);                     \
    l = fmaf(l, alpha, (p0 + p1) + (p2 + p3));                              \
    half4 pf; pf[0] = (f16)p0; pf[1] = (f16)p1;                             \
    pf[2] = (f16)p2; pf[3] = (f16)p3;                                       \
    _Pragma("unroll")                                                       \
    for (int ct = 0; ct < 4; ++ct) {                                        \
        float4v o_ = accO[ct];                                              \
        o_[0] *= alpha; o_[1] *= alpha; o_[2] *= alpha; o_[3] *= alpha;     \
        accO[ct] = __builtin_amdgcn_mfma_f32_16x16x16f16(                   \
            gvf[B][ct], pf, o_, 0, 0, 0);                                   \
    }                                                                       \
} while (0)

    for (int i2 = 0; i2 < 32; ++i2) {
        const int kA = kt0 + i2*32;
        STEP(0, 1, kA + 16, true);
        STEP(1, 0, kA + 32, (i2 < 31));
    }

    // full row-sum: reduce l across the 4 quads
    l += __shfl_xor(l, 16);
    l += __shfl_xor(l, 32);

    if (w > 0) {
        #pragma unroll
        for (int ct = 0; ct < 4; ++ct)
            #pragma unroll
            for (int r = 0; r < 4; ++r)
                Obuf[w-1][ct*16 + kb*4 + r][m16] = accO[ct][r];
        if (kb == 0) { Mbuf[w-1][m16] = m; Lbuf[w-1][m16] = l; }
    }
    __syncthreads();

    if (w == 0) {
        float M = m;
        M = fmaxf(M, Mbuf[0][m16]);
        M = fmaxf(M, Mbuf[1][m16]);
        M = fmaxf(M, Mbuf[2][m16]);
        float f0  = __expf(m - M);
        float fi0 = __expf(Mbuf[0][m16] - M);
        float fi1 = __expf(Mbuf[1][m16] - M);
        float fi2 = __expf(Mbuf[2][m16] - M);
        float lt  = l*f0 + Lbuf[0][m16]*fi0 + Lbuf[1][m16]*fi1 + Lbuf[2][m16]*fi2;
        float inv = 1.0f / lt;
        #pragma unroll
        for (int ct = 0; ct < 4; ++ct) {
            #pragma unroll
            for (int r = 0; r < 4; ++r) {
                int ch = ct*16 + kb*4 + r;
                float o = accO[ct][r]*f0
                        + Obuf[0][ch][m16]*fi0
                        + Obuf[1][ch][m16]*fi1
                        + Obuf[2][ch][m16]*fi2;
                out[((size_t)n*CC + ch)*HW + q0 + m16] = o * inv;
            }
        }
    }
#undef STEP
#undef LOADK
}

// ---------------------------------------------------------------------------
extern "C" void kernel_launch(void* const* d_in, const int* in_sizes, int n_in,
                              void* d_out, int out_size, void* d_ws, size_t ws_size,
                              hipStream_t stream)
{
    const float* low   = (const float*)d_in[0];
    const float* h0    = (const float*)d_in[1];
    const float* h1    = (const float*)d_in[2];
    const float* Wq    = (const float*)d_in[3];
    const float* bq    = (const float*)d_in[4];
    const float* gq    = (const float*)d_in[5];
    const float* betaq = (const float*)d_in[6];
    const float* Wk    = (const float*)d_in[7];
    const float* bk    = (const float*)d_in[8];
    const float* gk    = (const float*)d_in[9];
    const float* betak = (const float*)d_in[10];
    const float* Wv    = (const float*)d_in[11];
    const float* bv    = (const float*)d_in[12];

    float* wsf = (float*)d_ws;
    float* out = (float*)d_out;

    f16* base = (f16*)((char*)d_ws + 2048);
    f16* qh = base;
    f16* ql = qh + NELEM;
    f16* kh = ql + NELEM;
    f16* kl = kh + NELEM;
    f16* gv = kl + NELEM;

    zero_stats_kernel<<<1, 256, 0, stream>>>(wsf);

    conv2_kernel<<<dim3(HW/64, NB), 512, 0, stream>>>(
        low, h0, h1, Wq, bq, Wk, bk, Wv, bv, wsf, qh, ql, kh, kl, gv);

    bnstats_kernel<<<1, 128, 0, stream>>>(gq, betaq, gk, betak, wsf);

    apply_kernel<<<dim3(NELEM/(256*8), 2), 256, 0, stream>>>(qh, ql, kh, kl, wsf);

    attn_kernel<<<dim3(HW/16, NB), 256, 0, stream>>>(qh, ql, kh, kl, gv, out);
}

// Round 6
// 289.573 us; speedup vs baseline: 4.3549x; 1.5926x over previous
//
#include <hip/hip_runtime.h>

#define NB 4
#define CC 64
#define HW 4096
#define NT (NB*HW)
#define EPSV 1e-5f
#define LOG2E 1.4426950408889634f

typedef _Float16 f16;
typedef _Float16 half4 __attribute__((ext_vector_type(4)));
typedef _Float16 half8 __attribute__((ext_vector_type(8)));
typedef float   float4v __attribute__((ext_vector_type(4)));

#define NELEM ((size_t)NB*HW*CC)   // 1,048,576 per tensor

// ws: fp32 [0..255] raw stats (sumq,ssqq,sumk,ssqk); [256..511] folded
// scale/shift (sq,tq,sk,tk — K pair pre-scaled by log2e).
// Byte 2048+: f16 q, k ([n][hw][c]) and gv ([n][c][hw]) — 3 x 2 MB.

__global__ void zero_stats_kernel(float* __restrict__ ws) { ws[threadIdx.x] = 0.0f; }

// ---------------------------------------------------------------------------
// conv2: 3 fused 1x1 convs, W staged in LDS (wave-uniform broadcast reads),
// f16 stores + fused BN stats. grid (HW/64, NB), 512 thr.
// ---------------------------------------------------------------------------
__global__ __launch_bounds__(512)
void conv2_kernel(const float* __restrict__ x,
                  const float* __restrict__ h0, const float* __restrict__ h1,
                  const float* __restrict__ Wq, const float* __restrict__ bq,
                  const float* __restrict__ Wk, const float* __restrict__ bk,
                  const float* __restrict__ Wv, const float* __restrict__ bv,
                  float* __restrict__ ws,
                  f16* __restrict__ q, f16* __restrict__ k, f16* __restrict__ gv)
{
    __shared__ float Wl[3][CC*CC];   // 48 KB
    __shared__ f16   xs[CC][64];     // 8 KB
    const int t   = threadIdx.x;
    const int n   = blockIdx.y;
    const int px0 = blockIdx.x * 64;
    const int px  = t & 63;
    const int grp = t >> 6;          // wave-uniform
    const int oc0 = grp * 8;

    {   // cooperative W load: 3 x 1024 float4
        const float4* a = (const float4*)Wq;
        const float4* b = (const float4*)Wk;
        const float4* c = (const float4*)Wv;
        float4* d0 = (float4*)Wl[0]; float4* d1 = (float4*)Wl[1]; float4* d2 = (float4*)Wl[2];
        d0[t] = a[t];  d0[t+512] = a[t+512];
        d1[t] = b[t];  d1[t+512] = b[t+512];
        d2[t] = c[t];  d2[t+512] = c[t+512];
    }
    for (int i = t; i < CC*64; i += 512) {
        int ic = i >> 6, p = i & 63;
        xs[ic][p] = (f16)x[((size_t)n*CC + ic)*HW + px0 + p];
    }
    __syncthreads();

    float aq[8], ak[8], av[8];
    #pragma unroll
    for (int j = 0; j < 8; ++j) { aq[j] = bq[oc0+j]; ak[j] = bk[oc0+j]; av[j] = bv[oc0+j]; }

    for (int ic = 0; ic < CC; ic += 4) {
        float xv0 = (float)xs[ic  ][px];
        float xv1 = (float)xs[ic+1][px];
        float xv2 = (float)xs[ic+2][px];
        float xv3 = (float)xs[ic+3][px];
        #pragma unroll
        for (int j = 0; j < 8; ++j) {
            const int row = (oc0+j)*CC + ic;
            float4 wq = *(const float4*)&Wl[0][row];
            float4 wk = *(const float4*)&Wl[1][row];
            float4 wv = *(const float4*)&Wl[2][row];
            aq[j] = fmaf(wq.x,xv0, fmaf(wq.y,xv1, fmaf(wq.z,xv2, fmaf(wq.w,xv3, aq[j]))));
            ak[j] = fmaf(wk.x,xv0, fmaf(wk.y,xv1, fmaf(wk.z,xv2, fmaf(wk.w,xv3, ak[j]))));
            av[j] = fmaf(wv.x,xv0, fmaf(wv.y,xv1, fmaf(wv.z,xv2, fmaf(wv.w,xv3, av[j]))));
        }
    }

    // raw q,k stores (f16, [hw][c] layout)
    const size_t base = ((size_t)n*HW + px0 + px)*CC + oc0;
    half8 vq, vk;
    #pragma unroll
    for (int j = 0; j < 8; ++j) { vq[j] = (f16)aq[j]; vk[j] = (f16)ak[j]; }
    *(half8*)&q[base] = vq;
    *(half8*)&k[base] = vk;

    // gated V ([c][hw] layout)
    #pragma unroll
    for (int j = 0; j < 8; ++j) {
        size_t gi = ((size_t)n*CC + oc0 + j)*HW + px0 + px;
        gv[gi] = (f16)((h0[gi] + h1[gi]) * av[j]);
    }

    // fused BN stats: full-wave reduce per channel, lane-0 atomics
    #pragma unroll
    for (int j = 0; j < 8; ++j) {
        float v0 = aq[j], v1 = aq[j]*aq[j], v2 = ak[j], v3 = ak[j]*ak[j];
        #pragma unroll
        for (int off = 32; off > 0; off >>= 1) {
            v0 += __shfl_down(v0, off);
            v1 += __shfl_down(v1, off);
            v2 += __shfl_down(v2, off);
            v3 += __shfl_down(v3, off);
        }
        if (px == 0) {
            atomicAdd(&ws[      oc0 + j], v0);
            atomicAdd(&ws[ 64 + oc0 + j], v1);
            atomicAdd(&ws[128 + oc0 + j], v2);
            atomicAdd(&ws[192 + oc0 + j], v3);
        }
    }
}

// ---------------------------------------------------------------------------
// Fold BN into scale/shift. K pair pre-multiplied by log2e (softmax uses exp2).
// ---------------------------------------------------------------------------
__global__ void bnstats_kernel(const float* __restrict__ gq, const float* __restrict__ betaq,
                               const float* __restrict__ gk, const float* __restrict__ betak,
                               float* __restrict__ ws)
{
    const int i = threadIdx.x;
    if (i < 64) {
        float mean = ws[i] * (1.0f / NT);
        float var  = ws[64 + i] * (1.0f / NT) - mean*mean;
        float s    = gq[i] * rsqrtf(var + EPSV);
        ws[256 + i] = s;
        ws[320 + i] = betaq[i] - mean*s;
    } else if (i < 128) {
        int c = i - 64;
        float mean = ws[128 + c] * (1.0f / NT);
        float var  = ws[192 + c] * (1.0f / NT) - mean*mean;
        float s    = gk[c] * rsqrtf(var + EPSV);
        ws[384 + c] = s * LOG2E;
        ws[448 + c] = (betak[c] - mean*s) * LOG2E;
    }
}

// ---------------------------------------------------------------------------
// apply: in-place y = relu(s*y + t) on the f16 tensors. blockIdx.y: 0=q, 1=k.
// ---------------------------------------------------------------------------
__global__ __launch_bounds__(256)
void apply_kernel(f16* __restrict__ q, f16* __restrict__ k,
                  const float* __restrict__ ws)
{
    __shared__ float sc[CC], sh[CC];
    const int t = threadIdx.x;
    const int tens = blockIdx.y;
    if (t < 64)       sc[t]    = ws[256 + tens*128 + t];
    else if (t < 128) sh[t-64] = ws[320 + tens*128 + (t-64)];
    __syncthreads();

    f16* p = tens ? k : q;
    const size_t e0 = ((size_t)blockIdx.x * 256 + t) * 8;
    const int c0 = (int)(e0 & 63);

    half8 v = *(half8*)&p[e0];
    half8 o;
    #pragma unroll
    for (int j = 0; j < 8; ++j)
        o[j] = (f16)fmaxf(fmaf(sc[c0+j], (float)v[j], sh[c0+j]), 0.0f);
    *(half8*)&p[e0] = o;
}

// ---------------------------------------------------------------------------
// MFMA flash attention, S^T form, single-f16, 2 Q-tiles x 32-key steps.
// grid (HW/32, NB), 256 thr. Wave w owns K-quarter [w*1024, +1024); 4-way
// LDS merge at the end. Scores arrive pre-scaled by log2e -> exp2 softmax.
// Layout (validated r4/r5): mfma(X,Y) -> D[p=quad*4+reg <- X row][q=lane&15 <- Y row].
// ---------------------------------------------------------------------------
__global__ __launch_bounds__(256, 2)
void attn_kernel(const f16* __restrict__ q, const f16* __restrict__ k,
                 const f16* __restrict__ gv, float* __restrict__ out)
{
    __shared__ float Obuf[3][CC][32];         // waves 1..3 partial O^T
    __shared__ float Mbuf[3][2][16], Lbuf[3][2][16];

    const int t    = threadIdx.x;
    const int n    = blockIdx.y;
    const int w    = t >> 6;
    const int lane = t & 63;
    const int m16  = lane & 15;
    const int kb   = lane >> 4;
    const int q0   = blockIdx.x * 32;

    // Q fragments (Y-operand) for 2 q-tiles
    half8 qf[2][2];
    #pragma unroll
    for (int qt = 0; qt < 2; ++qt) {
        const size_t qb = ((size_t)n*HW + q0 + qt*16 + m16)*CC + kb*8;
        qf[qt][0] = *(const half8*)&q[qb];
        qf[qt][1] = *(const half8*)&q[qb + 32];
    }

    const int    kt0   = w * (HW/4);
    const size_t krow  = (size_t)n*HW*CC;
    const size_t gbase = ((size_t)n*CC + m16)*HW;

    half8 khf[2][2][2];   // [buf][ktile][chalf]
    half4 gvf[2][4];      // [ktile][ct]

#define LOADK(B, KT) do {                                                     \
    size_t a_ = krow + ((size_t)(KT) + m16)*CC + kb*8;                        \
    khf[B][0][0] = *(const half8*)&k[a_];                                     \
    khf[B][0][1] = *(const half8*)&k[a_ + 32];                                \
    khf[B][1][0] = *(const half8*)&k[a_ + 16*CC];                             \
    khf[B][1][1] = *(const half8*)&k[a_ + 16*CC + 32];                        \
} while (0)

#define LOADGV(KT) do {                                                       \
    size_t g_ = gbase + (size_t)(KT) + kb*4;                                  \
    _Pragma("unroll") for (int k2 = 0; k2 < 2; ++k2)                          \
    _Pragma("unroll") for (int ct = 0; ct < 4; ++ct)                          \
        gvf[k2][ct] = *(const half4*)&gv[g_ + k2*16 + (size_t)ct*16*HW];      \
} while (0)

    LOADK(0, kt0);

    float4v accO[2][4];
    #pragma unroll
    for (int qt = 0; qt < 2; ++qt)
        #pragma unroll
        for (int ct = 0; ct < 4; ++ct) accO[qt][ct] = (float4v){0.f,0.f,0.f,0.f};
    float m[2] = {-INFINITY, -INFINITY}, l[2] = {0.f, 0.f};

#define STEP(B, NB_, KT, KTN) do {                                            \
    LOADGV(KT);                                                               \
    LOADK(NB_, KTN);                                                          \
    float4v accS[2][2];                                                       \
    _Pragma("unroll") for (int qt = 0; qt < 2; ++qt)                          \
    _Pragma("unroll") for (int k2 = 0; k2 < 2; ++k2) {                        \
        float4v z_ = {0.f,0.f,0.f,0.f};                                       \
        z_ = __builtin_amdgcn_mfma_f32_16x16x32_f16(khf[B][k2][0], qf[qt][0], z_, 0,0,0); \
        accS[qt][k2] = __builtin_amdgcn_mfma_f32_16x16x32_f16(khf[B][k2][1], qf[qt][1], z_, 0,0,0); \
    }                                                                         \
    _Pragma("unroll") for (int qt = 0; qt < 2; ++qt) {                        \
        float mx = fmaxf(fmaxf(fmaxf(accS[qt][0][0], accS[qt][0][1]),         \
                               fmaxf(accS[qt][0][2], accS[qt][0][3])),        \
                         fmaxf(fmaxf(accS[qt][1][0], accS[qt][1][1]),         \
                               fmaxf(accS[qt][1][2], accS[qt][1][3])));       \
        mx = fmaxf(mx, __shfl_xor(mx, 16));                                   \
        mx = fmaxf(mx, __shfl_xor(mx, 32));                                   \
        float mn = fmaxf(m[qt], mx);                                          \
        float al = exp2f(m[qt] - mn);  m[qt] = mn;                            \
        float p0 = exp2f(accS[qt][0][0]-mn), p1 = exp2f(accS[qt][0][1]-mn);   \
        float p2 = exp2f(accS[qt][0][2]-mn), p3 = exp2f(accS[qt][0][3]-mn);   \
        float p4 = exp2f(accS[qt][1][0]-mn), p5 = exp2f(accS[qt][1][1]-mn);   \
        float p6 = exp2f(accS[qt][1][2]-mn), p7 = exp2f(accS[qt][1][3]-mn);   \
        l[qt] = fmaf(l[qt], al, ((p0+p1)+(p2+p3)) + ((p4+p5)+(p6+p7)));       \
        half4 pfa, pfb;                                                       \
        pfa[0]=(f16)p0; pfa[1]=(f16)p1; pfa[2]=(f16)p2; pfa[3]=(f16)p3;       \
        pfb[0]=(f16)p4; pfb[1]=(f16)p5; pfb[2]=(f16)p6; pfb[3]=(f16)p7;       \
        _Pragma("unroll") for (int ct = 0; ct < 4; ++ct) {                    \
            float4v o_ = accO[qt][ct];                                        \
            o_[0]*=al; o_[1]*=al; o_[2]*=al; o_[3]*=al;                       \
            o_ = __builtin_amdgcn_mfma_f32_16x16x16f16(gvf[0][ct], pfa, o_, 0,0,0); \
            accO[qt][ct] = __builtin_amdgcn_mfma_f32_16x16x16f16(gvf[1][ct], pfb, o_, 0,0,0); \
        }                                                                     \
    }                                                                         \
} while (0)

    for (int i2 = 0; i2 < 16; ++i2) {
        const int kA = kt0 + i2*64;
        STEP(0, 1, kA,      kA + 32);
        STEP(1, 0, kA + 32, kA + 64);   // final prefetch overreads into gv: unused
    }

    // full l per q-row: reduce across the 4 quads
    #pragma unroll
    for (int qt = 0; qt < 2; ++qt) {
        l[qt] += __shfl_xor(l[qt], 16);
        l[qt] += __shfl_xor(l[qt], 32);
    }

    if (w > 0) {
        #pragma unroll
        for (int qt = 0; qt < 2; ++qt)
            #pragma unroll
            for (int ct = 0; ct < 4; ++ct)
                #pragma unroll
                for (int r = 0; r < 4; ++r)
                    Obuf[w-1][ct*16 + kb*4 + r][qt*16 + m16] = accO[qt][ct][r];
        if (kb == 0) {
            #pragma unroll
            for (int qt = 0; qt < 2; ++qt) {
                Mbuf[w-1][qt][m16] = m[qt];
                Lbuf[w-1][qt][m16] = l[qt];
            }
        }
    }
    __syncthreads();

    if (w == 0) {
        #pragma unroll
        for (int qt = 0; qt < 2; ++qt) {
            float M = m[qt];
            M = fmaxf(M, Mbuf[0][qt][m16]);
            M = fmaxf(M, Mbuf[1][qt][m16]);
            M = fmaxf(M, Mbuf[2][qt][m16]);
            float f0  = exp2f(m[qt] - M);
            float fi0 = exp2f(Mbuf[0][qt][m16] - M);
            float fi1 = exp2f(Mbuf[1][qt][m16] - M);
            float fi2 = exp2f(Mbuf[2][qt][m16] - M);
            float lt  = l[qt]*f0 + Lbuf[0][qt][m16]*fi0
                      + Lbuf[1][qt][m16]*fi1 + Lbuf[2][qt][m16]*fi2;
            float inv = 1.0f / lt;
            #pragma unroll
            for (int ct = 0; ct < 4; ++ct) {
                #pragma unroll
                for (int r = 0; r < 4; ++r) {
                    int ch = ct*16 + kb*4 + r;
                    int row = qt*16 + m16;
                    float o = accO[qt][ct][r]*f0
                            + Obuf[0][ch][row]*fi0
                            + Obuf[1][ch][row]*fi1
                            + Obuf[2][ch][row]*fi2;
                    out[((size_t)n*CC + ch)*HW + q0 + row] = o * inv;
                }
            }
        }
    }
#undef STEP
#undef LOADGV
#undef LOADK
}

// ---------------------------------------------------------------------------
extern "C" void kernel_launch(void* const* d_in, const int* in_sizes, int n_in,
                              void* d_out, int out_size, void* d_ws, size_t ws_size,
                              hipStream_t stream)
{
    const float* low   = (const float*)d_in[0];
    const float* h0    = (const float*)d_in[1];
    const float* h1    = (const float*)d_in[2];
    const float* Wq    = (const float*)d_in[3];
    const float* bq    = (const float*)d_in[4];
    const float* gq    = (const float*)d_in[5];
    const float* betaq = (const float*)d_in[6];
    const float* Wk    = (const float*)d_in[7];
    const float* bk    = (const float*)d_in[8];
    const float* gk    = (const float*)d_in[9];
    const float* betak = (const float*)d_in[10];
    const float* Wv    = (const float*)d_in[11];
    const float* bv    = (const float*)d_in[12];

    float* wsf = (float*)d_ws;
    float* out = (float*)d_out;

    f16* q  = (f16*)((char*)d_ws + 2048);
    f16* k  = q + NELEM;
    f16* gv = k + NELEM;

    zero_stats_kernel<<<1, 256, 0, stream>>>(wsf);

    conv2_kernel<<<dim3(HW/64, NB), 512, 0, stream>>>(
        low, h0, h1, Wq, bq, Wk, bk, Wv, bv, wsf, q, k, gv);

    bnstats_kernel<<<1, 128, 0, stream>>>(gq, betaq, gk, betak, wsf);

    apply_kernel<<<dim3((int)(NELEM/(256*8)), 2), 256, 0, stream>>>(q, k, wsf);

    attn_kernel<<<dim3(HW/32, NB), 256, 0, stream>>>(q, k, gv, out);
}

// Round 7
// 231.880 us; speedup vs baseline: 5.4384x; 1.2488x over previous
//
#include <hip/hip_runtime.h>

#define NB 4
#define CC 64
#define HW 4096
#define NT (NB*HW)
#define EPSV 1e-5f
#define LOG2E 1.4426950408889634f

typedef _Float16 f16;
typedef _Float16 half4 __attribute__((ext_vector_type(4)));
typedef _Float16 half8 __attribute__((ext_vector_type(8)));
typedef float   float4v __attribute__((ext_vector_type(4)));

#define NELEM ((size_t)NB*HW*CC)   // 1,048,576 per tensor

// ws: fp32 [256..511] folded scale/shift (sq,tq,sk,tk — K pair pre-scaled by
// log2e). [512..512+65536): per-block partial BN stats (256 blocks x 256).
// Byte 264192+: f16 q, k ([n][hw][c]) and gv ([n][c][hw]) — 3 x 2 MB.
#define PART_OFF 512
#define TEN_OFF  264192

// ---------------------------------------------------------------------------
// conv2: 3 fused 1x1 convs, W staged in LDS, f16 stores + per-wave partial
// BN stats to private global slots (NO atomics). grid (HW/64, NB), 512 thr.
// ---------------------------------------------------------------------------
__global__ __launch_bounds__(512)
void conv2_kernel(const float* __restrict__ x,
                  const float* __restrict__ h0, const float* __restrict__ h1,
                  const float* __restrict__ Wq, const float* __restrict__ bq,
                  const float* __restrict__ Wk, const float* __restrict__ bk,
                  const float* __restrict__ Wv, const float* __restrict__ bv,
                  float* __restrict__ ws,
                  f16* __restrict__ q, f16* __restrict__ k, f16* __restrict__ gv)
{
    __shared__ float Wl[3][CC*CC];   // 48 KB
    __shared__ f16   xs[CC][64];     // 8 KB
    const int t   = threadIdx.x;
    const int n   = blockIdx.y;
    const int px0 = blockIdx.x * 64;
    const int px  = t & 63;
    const int grp = t >> 6;          // wave-uniform
    const int oc0 = grp * 8;

    {   // cooperative W load: 3 x 1024 float4
        const float4* a = (const float4*)Wq;
        const float4* b = (const float4*)Wk;
        const float4* c = (const float4*)Wv;
        float4* d0 = (float4*)Wl[0]; float4* d1 = (float4*)Wl[1]; float4* d2 = (float4*)Wl[2];
        d0[t] = a[t];  d0[t+512] = a[t+512];
        d1[t] = b[t];  d1[t+512] = b[t+512];
        d2[t] = c[t];  d2[t+512] = c[t+512];
    }
    for (int i = t; i < CC*64; i += 512) {
        int ic = i >> 6, p = i & 63;
        xs[ic][p] = (f16)x[((size_t)n*CC + ic)*HW + px0 + p];
    }
    __syncthreads();

    float aq[8], ak[8], av[8];
    #pragma unroll
    for (int j = 0; j < 8; ++j) { aq[j] = bq[oc0+j]; ak[j] = bk[oc0+j]; av[j] = bv[oc0+j]; }

    for (int ic = 0; ic < CC; ic += 4) {
        float xv0 = (float)xs[ic  ][px];
        float xv1 = (float)xs[ic+1][px];
        float xv2 = (float)xs[ic+2][px];
        float xv3 = (float)xs[ic+3][px];
        #pragma unroll
        for (int j = 0; j < 8; ++j) {
            const int row = (oc0+j)*CC + ic;
            float4 wq = *(const float4*)&Wl[0][row];
            float4 wk = *(const float4*)&Wl[1][row];
            float4 wv = *(const float4*)&Wl[2][row];
            aq[j] = fmaf(wq.x,xv0, fmaf(wq.y,xv1, fmaf(wq.z,xv2, fmaf(wq.w,xv3, aq[j]))));
            ak[j] = fmaf(wk.x,xv0, fmaf(wk.y,xv1, fmaf(wk.z,xv2, fmaf(wk.w,xv3, ak[j]))));
            av[j] = fmaf(wv.x,xv0, fmaf(wv.y,xv1, fmaf(wv.z,xv2, fmaf(wv.w,xv3, av[j]))));
        }
    }

    // raw q,k stores (f16, [hw][c] layout)
    const size_t base = ((size_t)n*HW + px0 + px)*CC + oc0;
    half8 vq, vk;
    #pragma unroll
    for (int j = 0; j < 8; ++j) { vq[j] = (f16)aq[j]; vk[j] = (f16)ak[j]; }
    *(half8*)&q[base] = vq;
    *(half8*)&k[base] = vk;

    // gated V ([c][hw] layout)
    #pragma unroll
    for (int j = 0; j < 8; ++j) {
        size_t gi = ((size_t)n*CC + oc0 + j)*HW + px0 + px;
        gv[gi] = (f16)((h0[gi] + h1[gi]) * av[j]);
    }

    // BN partial stats: full-wave reduce per channel, lane-0 stores to a
    // private slot (no atomics — r6's 65k same-line atomicAdds were 100 µs).
    float* slot = ws + PART_OFF + (size_t)(n*(HW/64) + blockIdx.x)*256;
    #pragma unroll
    for (int j = 0; j < 8; ++j) {
        float v0 = aq[j], v1 = aq[j]*aq[j], v2 = ak[j], v3 = ak[j]*ak[j];
        #pragma unroll
        for (int off = 32; off > 0; off >>= 1) {
            v0 += __shfl_down(v0, off);
            v1 += __shfl_down(v1, off);
            v2 += __shfl_down(v2, off);
            v3 += __shfl_down(v3, off);
        }
        if (px == 0) {
            slot[      oc0 + j] = v0;
            slot[ 64 + oc0 + j] = v1;
            slot[128 + oc0 + j] = v2;
            slot[192 + oc0 + j] = v3;
        }
    }
}

// ---------------------------------------------------------------------------
// bnstats: tree-sum the 256 per-block partials, fold BN into scale/shift.
// K pair pre-multiplied by log2e (softmax uses exp2). 1 block x 256 thr.
// ---------------------------------------------------------------------------
__global__ __launch_bounds__(256)
void bnstats_kernel(const float* __restrict__ gq, const float* __restrict__ betaq,
                    const float* __restrict__ gk, const float* __restrict__ betak,
                    float* __restrict__ ws)
{
    __shared__ float tot[256];
    const int i = threadIdx.x;
    float acc = 0.0f;
    #pragma unroll 8
    for (int b = 0; b < 256; ++b) acc += ws[PART_OFF + b*256 + i];
    tot[i] = acc;
    __syncthreads();

    if (i < 64) {
        float mean = tot[i] * (1.0f / NT);
        float var  = tot[64 + i] * (1.0f / NT) - mean*mean;
        float s    = gq[i] * rsqrtf(var + EPSV);
        ws[256 + i] = s;
        ws[320 + i] = betaq[i] - mean*s;
    } else if (i < 128) {
        int c = i - 64;
        float mean = tot[128 + c] * (1.0f / NT);
        float var  = tot[192 + c] * (1.0f / NT) - mean*mean;
        float s    = gk[c] * rsqrtf(var + EPSV);
        ws[384 + c] = s * LOG2E;
        ws[448 + c] = (betak[c] - mean*s) * LOG2E;
    }
}

// ---------------------------------------------------------------------------
// apply: in-place y = relu(s*y + t) on the f16 tensors. blockIdx.y: 0=q, 1=k.
// ---------------------------------------------------------------------------
__global__ __launch_bounds__(256)
void apply_kernel(f16* __restrict__ q, f16* __restrict__ k,
                  const float* __restrict__ ws)
{
    __shared__ float sc[CC], sh[CC];
    const int t = threadIdx.x;
    const int tens = blockIdx.y;
    if (t < 64)       sc[t]    = ws[256 + tens*128 + t];
    else if (t < 128) sh[t-64] = ws[320 + tens*128 + (t-64)];
    __syncthreads();

    f16* p = tens ? k : q;
    const size_t e0 = ((size_t)blockIdx.x * 256 + t) * 8;
    const int c0 = (int)(e0 & 63);

    half8 v = *(half8*)&p[e0];
    half8 o;
    #pragma unroll
    for (int j = 0; j < 8; ++j)
        o[j] = (f16)fmaxf(fmaf(sc[c0+j], (float)v[j], sh[c0+j]), 0.0f);
    *(half8*)&p[e0] = o;
}

// ---------------------------------------------------------------------------
// MFMA flash attention, S^T form, TWO-PASS (exact global row max, then a
// rescale-free accumulate pass — no cross-lane ops in either hot loop).
// grid (HW/32, NB), 256 thr. Wave w owns K-quarter [w*1024, +1024); plain-sum
// merge at the end (all waves share M). Scores pre-scaled by log2e -> exp2.
// Layout (validated r4-r6): mfma(X,Y) -> D[p=quad*4+reg <- X row][q=lane&15 <- Y row].
// ---------------------------------------------------------------------------
__global__ __launch_bounds__(256, 2)
void attn_kernel(const f16* __restrict__ q, const f16* __restrict__ k,
                 const f16* __restrict__ gv, float* __restrict__ out)
{
    __shared__ float Obuf[3][CC][32];         // waves 1..3 partial O^T
    __shared__ float Mbuf[4][2][16];
    __shared__ float Lbuf[3][2][16];

    const int t    = threadIdx.x;
    const int n    = blockIdx.y;
    const int w    = t >> 6;
    const int lane = t & 63;
    const int m16  = lane & 15;
    const int kb   = lane >> 4;
    const int q0   = blockIdx.x * 32;

    // Q fragments (Y-operand) for 2 q-tiles
    half8 qf[2][2];
    #pragma unroll
    for (int qt = 0; qt < 2; ++qt) {
        const size_t qb = ((size_t)n*HW + q0 + qt*16 + m16)*CC + kb*8;
        qf[qt][0] = *(const half8*)&q[qb];
        qf[qt][1] = *(const half8*)&q[qb + 32];
    }

    const int    kt0   = w * (HW/4);
    const size_t krow  = (size_t)n*HW*CC;
    const size_t gbase = ((size_t)n*CC + m16)*HW;

    half8 khf[2][2][2];     // [buf][ktile][chalf]
    half4 gvf[2][2][4];     // [buf][ktile][ct]

#define LOADK(B, KT) do {                                                     \
    size_t a_ = krow + ((size_t)(KT) + m16)*CC + kb*8;                        \
    khf[B][0][0] = *(const half8*)&k[a_];                                     \
    khf[B][0][1] = *(const half8*)&k[a_ + 32];                                \
    khf[B][1][0] = *(const half8*)&k[a_ + 16*CC];                             \
    khf[B][1][1] = *(const half8*)&k[a_ + 16*CC + 32];                        \
} while (0)

#define LOADGV(B, KT) do {                                                    \
    size_t g_ = gbase + (size_t)(KT) + kb*4;                                  \
    _Pragma("unroll") for (int k2_ = 0; k2_ < 2; ++k2_)                       \
    _Pragma("unroll") for (int ct_ = 0; ct_ < 4; ++ct_)                       \
        gvf[B][k2_][ct_] = *(const half4*)&gv[g_ + k2_*16 + (size_t)ct_*16*HW];\
} while (0)

#define SMFMA(B, accS) do {                                                   \
    _Pragma("unroll") for (int qt_ = 0; qt_ < 2; ++qt_)                       \
    _Pragma("unroll") for (int k2_ = 0; k2_ < 2; ++k2_) {                     \
        float4v z_ = {0.f,0.f,0.f,0.f};                                       \
        z_ = __builtin_amdgcn_mfma_f32_16x16x32_f16(khf[B][k2_][0], qf[qt_][0], z_, 0,0,0); \
        accS[qt_][k2_] = __builtin_amdgcn_mfma_f32_16x16x32_f16(khf[B][k2_][1], qf[qt_][1], z_, 0,0,0); \
    }                                                                         \
} while (0)

    // ---------------- pass 1: exact global row max (no cross-lane in loop)
    float mloc[2] = {-INFINITY, -INFINITY};

#define STEP1(B, NB_, KTN) do {                                               \
    LOADK(NB_, KTN);                                                          \
    float4v accS[2][2];                                                       \
    SMFMA(B, accS);                                                           \
    _Pragma("unroll") for (int qt_ = 0; qt_ < 2; ++qt_) {                     \
        float a_ = fmaxf(fmaxf(fmaxf(accS[qt_][0][0], accS[qt_][0][1]),       \
                               fmaxf(accS[qt_][0][2], accS[qt_][0][3])),      \
                         fmaxf(fmaxf(accS[qt_][1][0], accS[qt_][1][1]),       \
                               fmaxf(accS[qt_][1][2], accS[qt_][1][3])));     \
        mloc[qt_] = fmaxf(mloc[qt_], a_);                                     \
    }                                                                         \
} while (0)

    LOADK(0, kt0);
    for (int i2 = 0; i2 < 16; ++i2) {
        const int kA = kt0 + i2*64;
        STEP1(0, 1, kA + 32);
        STEP1(1, 0, kA + 64);   // final prefetch overreads into gv region: unused, in-bounds of ws
    }

    #pragma unroll
    for (int qt = 0; qt < 2; ++qt) {
        mloc[qt] = fmaxf(mloc[qt], __shfl_xor(mloc[qt], 16));
        mloc[qt] = fmaxf(mloc[qt], __shfl_xor(mloc[qt], 32));
    }
    if (kb == 0) { Mbuf[w][0][m16] = mloc[0]; Mbuf[w][1][m16] = mloc[1]; }
    __syncthreads();

    float M[2];
    #pragma unroll
    for (int qt = 0; qt < 2; ++qt)
        M[qt] = fmaxf(fmaxf(Mbuf[0][qt][m16], Mbuf[1][qt][m16]),
                      fmaxf(Mbuf[2][qt][m16], Mbuf[3][qt][m16]));

    // ---------------- pass 2: rescale-free accumulate
    float4v accO[2][4];
    #pragma unroll
    for (int qt = 0; qt < 2; ++qt)
        #pragma unroll
        for (int ct = 0; ct < 4; ++ct) accO[qt][ct] = (float4v){0.f,0.f,0.f,0.f};
    float l[2] = {0.f, 0.f};

#define STEP2(B, NB_, KTN) do {                                               \
    LOADK(NB_, KTN);                                                          \
    LOADGV(NB_, KTN);                                                         \
    float4v accS[2][2];                                                       \
    SMFMA(B, accS);                                                           \
    _Pragma("unroll") for (int qt_ = 0; qt_ < 2; ++qt_) {                     \
        float p0 = exp2f(accS[qt_][0][0] - M[qt_]);                           \
        float p1 = exp2f(accS[qt_][0][1] - M[qt_]);                           \
        float p2 = exp2f(accS[qt_][0][2] - M[qt_]);                           \
        float p3 = exp2f(accS[qt_][0][3] - M[qt_]);                           \
        float p4 = exp2f(accS[qt_][1][0] - M[qt_]);                           \
        float p5 = exp2f(accS[qt_][1][1] - M[qt_]);                           \
        float p6 = exp2f(accS[qt_][1][2] - M[qt_]);                           \
        float p7 = exp2f(accS[qt_][1][3] - M[qt_]);                           \
        l[qt_] += ((p0+p1)+(p2+p3)) + ((p4+p5)+(p6+p7));                      \
        half4 pfa, pfb;                                                       \
        pfa[0]=(f16)p0; pfa[1]=(f16)p1; pfa[2]=(f16)p2; pfa[3]=(f16)p3;       \
        pfb[0]=(f16)p4; pfb[1]=(f16)p5; pfb[2]=(f16)p6; pfb[3]=(f16)p7;       \
        _Pragma("unroll") for (int ct_ = 0; ct_ < 4; ++ct_) {                 \
            float4v o_ = accO[qt_][ct_];                                      \
            o_ = __builtin_amdgcn_mfma_f32_16x16x16f16(gvf[B][0][ct_], pfa, o_, 0,0,0); \
            accO[qt_][ct_] = __builtin_amdgcn_mfma_f32_16x16x16f16(gvf[B][1][ct_], pfb, o_, 0,0,0); \
        }                                                                     \
    }                                                                         \
} while (0)

    LOADK(0, kt0);
    LOADGV(0, kt0);
    for (int i2 = 0; i2 < 16; ++i2) {
        const int kA = kt0 + i2*64;
        STEP2(0, 1, kA + 32);
        STEP2(1, 0, kA + 64);   // final prefetch overread: unused, in-bounds of ws
    }

    // l per q-row: reduce across the 4 quads (once)
    #pragma unroll
    for (int qt = 0; qt < 2; ++qt) {
        l[qt] += __shfl_xor(l[qt], 16);
        l[qt] += __shfl_xor(l[qt], 32);
    }

    if (w > 0) {
        #pragma unroll
        for (int qt = 0; qt < 2; ++qt)
            #pragma unroll
            for (int ct = 0; ct < 4; ++ct)
                #pragma unroll
                for (int r = 0; r < 4; ++r)
                    Obuf[w-1][ct*16 + kb*4 + r][qt*16 + m16] = accO[qt][ct][r];
        if (kb == 0) {
            Lbuf[w-1][0][m16] = l[0];
            Lbuf[w-1][1][m16] = l[1];
        }
    }
    __syncthreads();

    if (w == 0) {
        #pragma unroll
        for (int qt = 0; qt < 2; ++qt) {
            float lt = l[qt] + Lbuf[0][qt][m16] + Lbuf[1][qt][m16] + Lbuf[2][qt][m16];
            float inv = 1.0f / lt;
            #pragma unroll
            for (int ct = 0; ct < 4; ++ct) {
                #pragma unroll
                for (int r = 0; r < 4; ++r) {
                    int ch  = ct*16 + kb*4 + r;
                    int row = qt*16 + m16;
                    float o = accO[qt][ct][r]
                            + Obuf[0][ch][row] + Obuf[1][ch][row] + Obuf[2][ch][row];
                    out[((size_t)n*CC + ch)*HW + q0 + row] = o * inv;
                }
            }
        }
    }
#undef STEP2
#undef STEP1
#undef SMFMA
#undef LOADGV
#undef LOADK
}

// ---------------------------------------------------------------------------
extern "C" void kernel_launch(void* const* d_in, const int* in_sizes, int n_in,
                              void* d_out, int out_size, void* d_ws, size_t ws_size,
                              hipStream_t stream)
{
    const float* low   = (const float*)d_in[0];
    const float* h0    = (const float*)d_in[1];
    const float* h1    = (const float*)d_in[2];
    const float* Wq    = (const float*)d_in[3];
    const float* bq    = (const float*)d_in[4];
    const float* gq    = (const float*)d_in[5];
    const float* betaq = (const float*)d_in[6];
    const float* Wk    = (const float*)d_in[7];
    const float* bk    = (const float*)d_in[8];
    const float* gk    = (const float*)d_in[9];
    const float* betak = (const float*)d_in[10];
    const float* Wv    = (const float*)d_in[11];
    const float* bv    = (const float*)d_in[12];

    float* wsf = (float*)d_ws;
    float* out = (float*)d_out;

    f16* q  = (f16*)((char*)d_ws + TEN_OFF);
    f16* k  = q + NELEM;
    f16* gv = k + NELEM;

    conv2_kernel<<<dim3(HW/64, NB), 512, 0, stream>>>(
        low, h0, h1, Wq, bq, Wk, bk, Wv, bv, wsf, q, k, gv);

    bnstats_kernel<<<1, 256, 0, stream>>>(gq, betaq, gk, betak, wsf);

    apply_kernel<<<dim3((int)(NELEM/(256*8)), 2), 256, 0, stream>>>(q, k, wsf);

    attn_kernel<<<dim3(HW/32, NB), 256, 0, stream>>>(q, k, gv, out);
}